// Round 10
// baseline (219.155 us; speedup 1.0000x reference)
//
#include <hip/hip_runtime.h>
#include <math.h>

// S4D via chunked linear-scan recurrence. x (L,B,D) f32, out (L,B,D) f32.
// R10: 3 kernels. K1 = chunk states + LDS group-total (kills pass2a/2b);
//      K3 = replay with in-prologue Horner scans of raw S and GT.
#define L_SEQ  4096
#define BSZ    4
#define DM     1024
#define NS     16
#define NSH    8                  // states per thread (n-split across wave halves)
#define NV     (NSH / 2)          // v2f vectors per array (2 states each)
#define NCHUNK 64
#define CHUNK  (L_SEQ / NCHUNK)   // 64
#define LOG2_CHUNK 6
#define GRP    8                  // chunks per scan group
#define NG     (NCHUNK / GRP)     // 8 groups
#define SCALE  0.25f
#define LBD    (BSZ * DM)         // 4096, x stride per l

typedef float v2f __attribute__((ext_vector_type(2)));

// ws layout:
//   qbuf float2[NS*DM]            128 KiB   (indexed n*DM + d)
//   pbuf float2[NS*DM]            128 KiB
//   S    float2[BSZ*NCHUNK*NS*DM] 33.5 MiB  raw chunk-final states
//   GT   float2[BSZ*NG*NS*DM]     4 MiB     raw group totals

// ---------------------------------------------------------------- params
__global__ void s4d_params(const float* __restrict__ log_dt,
                           const float* __restrict__ log_A_real,
                           const float* __restrict__ A_imag,
                           const float* __restrict__ Bp,
                           const float* __restrict__ Cp,
                           float2* __restrict__ qbuf,
                           float2* __restrict__ pbuf) {
    int t = blockIdx.x * blockDim.x + threadIdx.x;   // t = n*DM + d
    if (t >= NS * DM) return;
    int n = t >> 10, d = t & (DM - 1);
    int i = d * NS + n;                              // input layout (D,N)
    float dt = expf(log_dt[d]);
    float Ar = -expf(log_A_real[i]);
    float Ai = A_imag[i];
    float ar = 0.5f * Ar * dt, ai = 0.5f * Ai * dt;  // dtA/2
    float den_r = 1.0f - ar, den_i = -ai;            // 1 - dtA/2
    float num_r = 1.0f + ar, num_i = ai;             // 1 + dtA/2
    float inv = 1.0f / (den_r * den_r + den_i * den_i);
    float qr = (num_r * den_r + num_i * den_i) * inv;
    float qi = (num_i * den_r - num_r * den_i) * inv;
    float B0 = Bp[2 * i], B1 = Bp[2 * i + 1];
    float C0 = Cp[2 * i], C1 = Cp[2 * i + 1];
    float ccr = B0 * C0 - B1 * C1;
    float cci = B0 * C1 + B1 * C0;
    float s = dt * inv * SCALE;
    float pr = (ccr * den_r + cci * den_i) * s;
    float pi = (cci * den_r - ccr * den_i) * s;
    qbuf[t] = make_float2(qr, qi);
    pbuf[t] = make_float2(pr, pi);
}

// ---------------------------------------------------------------- K1
// Block = (b, dblk of 32, group g); 8 waves = the 8 chunks of the group.
// Each wave: 64-step chunk from h=0 -> write F to S and LDS.
// Wave 7 Horner-combines the 8 finals -> raw group total GT[b][g].
__attribute__((amdgpu_waves_per_eu(6, 8)))
__global__ __launch_bounds__(512)
void s4d_pass1(const float* __restrict__ x,
               const float2* __restrict__ qbuf,
               float2* __restrict__ S,
               float2* __restrict__ GT) {
    __shared__ float2 ldsF[GRP * NS * 32];           // [w][n][dlo] 32 KiB
    int lane = threadIdx.x & 63;
    int dlo  = lane & 31;
    int half = lane >> 5;
    int w    = threadIdx.x >> 6;                     // chunk within group
    int bx   = blockIdx.x;
    int g    = bx & (NG - 1);
    int dhi  = (bx >> 3) & 31;
    int b    = bx >> 8;
    int d    = dhi * 32 + dlo;
    int c    = g * GRP + w;
    int nb   = half * NSH;

    v2f Qr[NV], Qi[NV], Hr[NV], Hi[NV];
#pragma unroll
    for (int k = 0; k < NV; ++k) {
        float2 a = qbuf[(nb + 2 * k) * DM + d];
        float2 bq = qbuf[(nb + 2 * k + 1) * DM + d];
        Qr[k] = (v2f){a.x, bq.x};
        Qi[k] = (v2f){a.y, bq.y};
        Hr[k] = (v2f){0.0f, 0.0f};
        Hi[k] = (v2f){0.0f, 0.0f};
    }
    const float* xp = x + (size_t)(c * CHUNK) * LBD + b * DM + d;
    float xa[8], xb[8], xc[8];
#define LOADX(ARR, L0)                                                        \
    { _Pragma("unroll")                                                       \
      for (int j = 0; j < 8; ++j) ARR[j] = xp[(size_t)((L0) + j) * LBD]; }
#define STEP1(XV)                                                             \
    { v2f X = {XV, XV};                                                       \
      _Pragma("unroll")                                                       \
      for (int k = 0; k < NV; ++k) {                                          \
          v2f nr = __builtin_elementwise_fma(Qr[k], Hr[k],                    \
                    __builtin_elementwise_fma(-Qi[k], Hi[k], X));             \
          v2f ni = __builtin_elementwise_fma(Qr[k], Hi[k], Qi[k] * Hr[k]);    \
          Hr[k] = nr; Hi[k] = ni;                                             \
      } }
#define COMP1(ARR)                                                            \
    { _Pragma("unroll")                                                       \
      for (int j = 0; j < 8; ++j) STEP1(ARR[j]) }
    LOADX(xa, 0)  LOADX(xb, 8)
    LOADX(xc, 16) COMP1(xa)
    LOADX(xa, 24) COMP1(xb)
    LOADX(xb, 32) COMP1(xc)
    LOADX(xc, 40) COMP1(xa)
    LOADX(xa, 48) COMP1(xb)
    LOADX(xb, 56) COMP1(xc)
    COMP1(xa)
    COMP1(xb)
#undef COMP1
#undef STEP1
#undef LOADX
    // write chunk-final state to global S and LDS
    float2* sp = S + ((size_t)(b * NCHUNK + c) * NS + nb) * DM + d;
#pragma unroll
    for (int k = 0; k < NV; ++k) {
        float2 f0 = make_float2(Hr[k].x, Hi[k].x);
        float2 f1 = make_float2(Hr[k].y, Hi[k].y);
        sp[(size_t)(2 * k) * DM]     = f0;
        sp[(size_t)(2 * k + 1) * DM] = f1;
        ldsF[(w * NS + nb + 2 * k) * 32 + dlo]     = f0;
        ldsF[(w * NS + nb + 2 * k + 1) * 32 + dlo] = f1;
    }
    __syncthreads();
    if (w == GRP - 1) {                              // wave 7: group total
#pragma unroll
        for (int k = 0; k < NV; ++k) {
            // qL = q^CHUNK
            v2f ar = Qr[k], ai = Qi[k];
#pragma unroll
            for (int i = 0; i < LOG2_CHUNK; ++i) {
                v2f nr = __builtin_elementwise_fma(-ai, ai, ar * ar);
                v2f ni = (ar + ar) * ai;
                ar = nr; ai = ni;
            }
            v2f tr = (v2f){0.0f, 0.0f}, ti = (v2f){0.0f, 0.0f};
#pragma unroll
            for (int w2 = 0; w2 < GRP; ++w2) {       // acc = qL*acc + F_w2
                float2 f0 = ldsF[(w2 * NS + nb + 2 * k) * 32 + dlo];
                float2 f1 = ldsF[(w2 * NS + nb + 2 * k + 1) * 32 + dlo];
                v2f Fr = (v2f){f0.x, f1.x};
                v2f Fi = (v2f){f0.y, f1.y};
                v2f nr = __builtin_elementwise_fma(ar, tr,
                          __builtin_elementwise_fma(-ai, ti, Fr));
                v2f ni = __builtin_elementwise_fma(ar, ti,
                          __builtin_elementwise_fma(ai, tr, Fi));
                tr = nr; ti = ni;
            }
            float2* gp = GT + ((size_t)(b * NG + g) * NS + nb) * DM + d;
            gp[(size_t)(2 * k) * DM]     = make_float2(tr.x, ti.x);
            gp[(size_t)(2 * k + 1) * DM] = make_float2(tr.y, ti.y);
        }
    }
}

// ---------------------------------------------------------------- K3
// 2 threads per (b,c,d), 8 states each. Prologue: Horner-scan raw GT
// (radix qC=qL^8, g iters) and raw S (radix qL, jj iters), combine,
// then replay 64 steps + fused SiLU epilogue. Main loop unchanged (R9).
__attribute__((amdgpu_waves_per_eu(4, 4)))
__global__ __launch_bounds__(256)
void s4d_pass3(const float* __restrict__ x,
               const float* __restrict__ Dp,
               const float2* __restrict__ qbuf,
               const float2* __restrict__ pbuf,
               const float2* __restrict__ S,
               const float2* __restrict__ GT,
               float* __restrict__ out) {
    int tid  = blockIdx.x * 256 + threadIdx.x;
    int lane = tid & 63;
    int dlo  = lane & 31;
    int half = lane >> 5;
    int u    = tid >> 6;
    int dhi  = u & 31;
    int bc   = u >> 5;
    int c    = bc & (NCHUNK - 1);
    int d    = dhi * 32 + dlo;
    int b    = bc >> LOG2_CHUNK;
    int nb   = half * NSH;
    int g    = c >> 3;                               // wave-uniform
    int jj   = c & 7;                                // wave-uniform

    v2f Qr[NV], Qi[NV], Pr[NV], Pi[NV], Hr[NV], Hi[NV];
#pragma unroll
    for (int k = 0; k < NV; ++k) {
        float2 a0 = qbuf[(nb + 2 * k) * DM + d];
        float2 a1 = qbuf[(nb + 2 * k + 1) * DM + d];
        float2 w0 = pbuf[(nb + 2 * k) * DM + d];
        float2 w1 = pbuf[(nb + 2 * k + 1) * DM + d];
        Qr[k] = (v2f){a0.x, a1.x};
        Qi[k] = (v2f){a0.y, a1.y};
        Pr[k] = (v2f){w0.x, w1.x};
        Pi[k] = (v2f){w0.y, w1.y};
    }
#pragma unroll
    for (int k = 0; k < NV; ++k) {
        // qL = q^CHUNK
        v2f ar = Qr[k], ai = Qi[k];
#pragma unroll
        for (int i = 0; i < LOG2_CHUNK; ++i) {
            v2f nr = __builtin_elementwise_fma(-ai, ai, ar * ar);
            v2f ni = (ar + ar) * ai;
            ar = nr; ai = ni;
        }
        v2f qLr = ar, qLi = ai;
        // w = qL^jj via square-and-multiply; a ends at qL^8 = qC
        v2f wr = (v2f){1.0f, 1.0f}, wi = (v2f){0.0f, 0.0f};
        if (jj & 1) {
            v2f tr = __builtin_elementwise_fma(-wi, ai, wr * ar);
            v2f ti = __builtin_elementwise_fma(wi, ar, wr * ai);
            wr = tr; wi = ti;
        }
        { v2f nr = __builtin_elementwise_fma(-ai, ai, ar * ar);
          v2f ni = (ar + ar) * ai; ar = nr; ai = ni; }      // qL^2
        if (jj & 2) {
            v2f tr = __builtin_elementwise_fma(-wi, ai, wr * ar);
            v2f ti = __builtin_elementwise_fma(wi, ar, wr * ai);
            wr = tr; wi = ti;
        }
        { v2f nr = __builtin_elementwise_fma(-ai, ai, ar * ar);
          v2f ni = (ar + ar) * ai; ar = nr; ai = ni; }      // qL^4
        if (jj & 4) {
            v2f tr = __builtin_elementwise_fma(-wi, ai, wr * ar);
            v2f ti = __builtin_elementwise_fma(wi, ar, wr * ai);
            wr = tr; wi = ti;
        }
        { v2f nr = __builtin_elementwise_fma(-ai, ai, ar * ar);
          v2f ni = (ar + ar) * ai; ar = nr; ai = ni; }      // qC = qL^8
        // chunk incoming: Horner over earlier group totals (radix qC)
        v2f cr = (v2f){0.0f, 0.0f}, ci = (v2f){0.0f, 0.0f};
        const float2* gp0 = GT + ((size_t)(b * NG) * NS + nb + 2 * k) * DM + d;
        const float2* gp1 = GT + ((size_t)(b * NG) * NS + nb + 2 * k + 1) * DM + d;
        for (int g2 = 0; g2 < g; ++g2) {             // uniform trip count
            float2 t0 = gp0[(size_t)g2 * NS * DM];
            float2 t1 = gp1[(size_t)g2 * NS * DM];
            v2f Tr = (v2f){t0.x, t1.x};
            v2f Ti = (v2f){t0.y, t1.y};
            v2f nr = __builtin_elementwise_fma(ar, cr,
                      __builtin_elementwise_fma(-ai, ci, Tr));
            v2f ni = __builtin_elementwise_fma(ar, ci,
                      __builtin_elementwise_fma(ai, cr, Ti));
            cr = nr; ci = ni;
        }
        // within-group: Horner over earlier chunk finals (radix qL)
        v2f sr = (v2f){0.0f, 0.0f}, si = (v2f){0.0f, 0.0f};
        const float2* fp0 = S + ((size_t)(b * NCHUNK + g * GRP) * NS + nb + 2 * k) * DM + d;
        const float2* fp1 = S + ((size_t)(b * NCHUNK + g * GRP) * NS + nb + 2 * k + 1) * DM + d;
        for (int j2 = 0; j2 < jj; ++j2) {            // uniform trip count
            float2 f0 = fp0[(size_t)j2 * NS * DM];
            float2 f1 = fp1[(size_t)j2 * NS * DM];
            v2f Fr = (v2f){f0.x, f1.x};
            v2f Fi = (v2f){f0.y, f1.y};
            v2f nr = __builtin_elementwise_fma(qLr, sr,
                      __builtin_elementwise_fma(-qLi, si, Fr));
            v2f ni = __builtin_elementwise_fma(qLr, si,
                      __builtin_elementwise_fma(qLi, sr, Fi));
            sr = nr; si = ni;
        }
        // H = within + qL^jj * chunk_incoming
        Hr[k] = __builtin_elementwise_fma(wr, cr,
                 __builtin_elementwise_fma(-wi, ci, sr));
        Hi[k] = __builtin_elementwise_fma(wr, ci,
                 __builtin_elementwise_fma(wi, cr, si));
    }
    float dpar = Dp[d];
    const float* xp = x + (size_t)(c * CHUNK) * LBD + b * DM + d;
    float* op = out + (size_t)(c * CHUNK) * LBD + b * DM + d;
    float xa[8], xb[8], xc[8];
#define LOADX(ARR, L0)                                                        \
    { _Pragma("unroll")                                                       \
      for (int j = 0; j < 8; ++j) ARR[j] = xp[(size_t)((L0) + j) * LBD]; }
#define COMP3(ARR, L0)                                                        \
    { float av[8];                                                            \
      _Pragma("unroll")                                                       \
      for (int j = 0; j < 8; ++j) {                                           \
          v2f X = {ARR[j], ARR[j]};                                           \
          v2f A = {0.0f, 0.0f};                                               \
          _Pragma("unroll")                                                   \
          for (int k = 0; k < NV; ++k) {                                      \
              v2f nr = __builtin_elementwise_fma(Qr[k], Hr[k],                \
                        __builtin_elementwise_fma(-Qi[k], Hi[k], X));         \
              v2f ni = __builtin_elementwise_fma(Qr[k], Hi[k],                \
                                                 Qi[k] * Hr[k]);              \
              Hr[k] = nr; Hi[k] = ni;                                         \
              A = __builtin_elementwise_fma(Pr[k], nr,                        \
                   __builtin_elementwise_fma(-Pi[k], ni, A));                 \
          }                                                                   \
          av[j] = A.x + A.y;                                                  \
      }                                                                       \
      _Pragma("unroll")                                                       \
      for (int j = 0; j < 8; ++j) av[j] += __shfl_xor(av[j], 32, 64);         \
      if (half == 0) {                                                        \
          _Pragma("unroll")                                                   \
          for (int j = 0; j < 8; ++j) {                                       \
              float z = fmaf(ARR[j], dpar, av[j]);                            \
              float sg = __builtin_amdgcn_rcpf(1.0f + __expf(-z));            \
              op[(size_t)((L0) + j) * LBD] = z * sg;                          \
          }                                                                   \
      } }
    LOADX(xa, 0)  LOADX(xb, 8)
    LOADX(xc, 16) COMP3(xa, 0)
    LOADX(xa, 24) COMP3(xb, 8)
    LOADX(xb, 32) COMP3(xc, 16)
    LOADX(xc, 40) COMP3(xa, 24)
    LOADX(xa, 48) COMP3(xb, 32)
    LOADX(xb, 56) COMP3(xc, 40)
    COMP3(xa, 48)
    COMP3(xb, 56)
#undef COMP3
#undef LOADX
}

// ---------------------------------------------------------------- launch
extern "C" void kernel_launch(void* const* d_in, const int* in_sizes, int n_in,
                              void* d_out, int out_size, void* d_ws, size_t ws_size,
                              hipStream_t stream) {
    const float* x          = (const float*)d_in[0];
    const float* log_dt     = (const float*)d_in[1];
    const float* log_A_real = (const float*)d_in[2];
    const float* A_imag     = (const float*)d_in[3];
    const float* Bp         = (const float*)d_in[4];
    const float* Cp         = (const float*)d_in[5];
    const float* Dp         = (const float*)d_in[6];
    float* out = (float*)d_out;

    float2* qbuf = (float2*)d_ws;
    float2* pbuf = qbuf + NS * DM;
    float2* S    = pbuf + NS * DM;
    float2* GT   = S + (size_t)BSZ * NCHUNK * NS * DM;

    hipLaunchKernelGGL(s4d_params, dim3((NS * DM) / 256), dim3(256), 0, stream,
                       log_dt, log_A_real, A_imag, Bp, Cp, qbuf, pbuf);
    hipLaunchKernelGGL(s4d_pass1, dim3(BSZ * (DM / 32) * NG), dim3(512), 0, stream,
                       x, qbuf, S, GT);
    hipLaunchKernelGGL(s4d_pass3, dim3((2 * BSZ * NCHUNK * DM) / 256), dim3(256), 0, stream,
                       x, Dp, qbuf, pbuf, S, GT, out);
}